// Round 8
// baseline (106.053 us; speedup 1.0000x reference)
//
#include <hip/hip_runtime.h>

typedef float  f32x4  __attribute__((ext_vector_type(4)));
typedef short  s16x8  __attribute__((ext_vector_type(8)));
typedef short  s16x4  __attribute__((ext_vector_type(4)));

#define NROWS (2048 * 128)
#define PASSES 8         // 16-row passes per wave
#define HS 104           // act LDS stride in shorts
#define EPSF 1e-8f

union Frag { s16x8 v; unsigned short u[8]; };

// fp32 -> bf16 RTNE (verified R3-R7)
__device__ __forceinline__ unsigned short f2bf(float f) {
    unsigned int u = __float_as_uint(f);
    u += 0x7fffu + ((u >> 16) & 1u);
    return (unsigned short)(u >> 16);
}

// ---------------------------------------------------------------------------
// Pre-kernel: repack weights to bf16 MFMA B-fragment order (unchanged).
// Contiguous in ws: w1(24576) w2(15360) w3(12288) b1(384) b2(320) b3(256).
// ---------------------------------------------------------------------------
__global__ void repack(const float* __restrict__ W1, const float* __restrict__ b1,
                       const float* __restrict__ W2, const float* __restrict__ b2,
                       const float* __restrict__ W3, const float* __restrict__ b3,
                       unsigned short* __restrict__ w1f, unsigned short* __restrict__ w2f,
                       unsigned short* __restrict__ w3f,
                       float* __restrict__ b1p, float* __restrict__ b2p,
                       float* __restrict__ b3p)
{
    const int b = blockIdx.x;
    const int l = threadIdx.x;      // 64 threads
    const int g = l >> 4, sl = l & 15;

    if (b < 24) {                   // W1: nt = b>>2, ks = b&3
        const int nt = b >> 2, ks = b & 3;
        const int o = nt * 16 + sl, kb = ks * 32 + g * 8;
        s16x8 v;
#pragma unroll
        for (int j = 0; j < 8; ++j) v[j] = (short)f2bf(W1[o * 128 + kb + j]);
        *(s16x8*)&w1f[b * 512 + l * 8] = v;
    } else if (b < 39) {            // W2 (out padded 72->80)
        const int f = b - 24, nt = f / 3, ks = f % 3;
        const int o = nt * 16 + sl, kb = ks * 32 + g * 8;
        s16x8 v;
#pragma unroll
        for (int j = 0; j < 8; ++j)
            v[j] = (short)((o < 72) ? f2bf(W2[o * 96 + kb + j]) : 0);
        *(s16x8*)&w2f[f * 512 + l * 8] = v;
    } else if (b < 51) {            // W3 (k padded 72->96)
        const int f = b - 39, nt = f / 3, ks = f % 3;
        const int o = nt * 16 + sl, kb = ks * 32 + g * 8;
        s16x8 v;
#pragma unroll
        for (int j = 0; j < 8; ++j)
            v[j] = (short)((kb + j < 72) ? f2bf(W3[o * 72 + kb + j]) : 0);
        *(s16x8*)&w3f[f * 512 + l * 8] = v;
    } else {                        // biases, zero-padded
        for (int i = l; i < 240; i += 64) {
            if (i < 96)       b1p[i] = b1[i];
            else if (i < 176) { int o = i - 96; b2p[o] = (o < 72) ? b2[o] : 0.f; }
            else              b3p[i - 176] = b3[i - 176];
        }
    }
}

// ---------------------------------------------------------------------------
// Main. 512 blocks x 256 thr. Weights staged to LDS once; each wave runs
// 8 passes of 16 rows. Per-pass register state is HALVED vs R5/R7
// (xp[8]=32 VGPR, D1[6]=24, frags 16) so phase-peak live ~90 VGPR fits the
// allocator's 128-VGPR occupancy target with NO SPILL (R5/R7 spilled ~41
// dwords/thread -> 21.6 MB scratch writes -> serialized ~900cyc reloads).
// x prefetched one pass ahead; act round-trip in wave-private LDS.
// ---------------------------------------------------------------------------
__global__ __launch_bounds__(256, 2)
void mlp_main(const float* __restrict__ x,
              const f32x4* __restrict__ wsrc,   // 3324 x 16 B = weights+biases
              float* __restrict__ acc /* [65]: s[64], uu */)
{
    __shared__ __align__(16) unsigned char  wb[53184];        // w1|w2|w3|b1|b2|b3
    __shared__ __align__(16) unsigned short act[4][16][HS];   // 13.3 KB wave-private
    __shared__ float sred[4][64];
    __shared__ float uured[4];

    const unsigned short* w1L = (const unsigned short*)wb;   // 24 frags
    const unsigned short* w2L = w1L + 12288;                 // 15 frags
    const unsigned short* w3L = w1L + 19968;                 // 12 frags
    const float* b1L = (const float*)(wb + 52224);           // 96
    const float* b2L = b1L + 96;                             // 80
    const float* b3L = b1L + 176;                            // 64

    const int tid  = threadIdx.x;
    const int lane = tid & 63;
    const int wv   = tid >> 6;
    const int g    = lane >> 4;
    const int sl   = lane & 15;

    // lane-fixed x address pattern: row sl, cols ks*32 + g*8 .. +7
    auto loadx = [&](f32x4 (&xp)[8], int p) {
        const float* xw = x + ((size_t)(blockIdx.x * 4 + wv) * (16 * PASSES) + p * 16) * 128;
#pragma unroll
        for (int ks = 0; ks < 4; ++ks) {
            const float* ptr = xw + sl * 128 + ks * 32 + g * 8;
            xp[ks * 2 + 0] = *(const f32x4*)ptr;
            xp[ks * 2 + 1] = *(const f32x4*)(ptr + 4);
        }
    };

    // ---- issue pass-0 x loads BEFORE weight staging (overlap) ----
    f32x4 xp[8];
    loadx(xp, 0);

    // ---- stage weights + biases to LDS (53184 B = 3324 f32x4) ----
    for (int i = tid; i < 3324; i += 256)
        ((f32x4*)wb)[i] = wsrc[i];
    __syncthreads();                      // weights visible to all waves

    float uu_part = 0.f;
    float s_part[4] = {0.f, 0.f, 0.f, 0.f};

    for (int p = 0; p < PASSES; ++p) {
        // convert this pass's x to A-frags (frees xp for the next prefetch)
        Frag A1[4];
#pragma unroll
        for (int ks = 0; ks < 4; ++ks)
#pragma unroll
            for (int j = 0; j < 4; ++j) {
                A1[ks].u[j]     = f2bf(xp[ks * 2 + 0][j]);
                A1[ks].u[4 + j] = f2bf(xp[ks * 2 + 1][j]);
            }

        // prefetch next pass (lands during L1+L2+L3 compute)
        if (p + 1 < PASSES) loadx(xp, p + 1);

        // ================= layer 1: 128 -> 96 =================
        f32x4 D1[6];
#pragma unroll
        for (int nt = 0; nt < 6; ++nt) {
            const float bb = b1L[nt * 16 + sl];
            D1[nt] = (f32x4){bb, bb, bb, bb};
        }
#pragma unroll
        for (int ks = 0; ks < 4; ++ks)
#pragma unroll
            for (int nt = 0; nt < 6; ++nt) {
                const s16x8 B = *(const s16x8*)&w1L[(nt * 4 + ks) * 512 + lane * 8];
                D1[nt] = __builtin_amdgcn_mfma_f32_16x16x32_bf16(A1[ks].v, B, D1[nt], 0, 0, 0);
            }
        // relu + write h1[sample = g*4+r][feat = nt*16+sl] (wave-private)
#pragma unroll
        for (int nt = 0; nt < 6; ++nt)
#pragma unroll
            for (int r = 0; r < 4; ++r)
                act[wv][g * 4 + r][nt * 16 + sl] = f2bf(fmaxf(D1[nt][r], 0.f));

        // layer-2 A-frags: feats 0..95 of sample sl
        Frag A2[3];
#pragma unroll
        for (int ks = 0; ks < 3; ++ks)
            A2[ks].v = *(const s16x8*)&act[wv][sl][ks * 32 + g * 8];

        // zero pad feats 80..95 for the h2 tile (read by L3 ks=2)
        {
            const s16x4 z = (s16x4){0, 0, 0, 0};
            *(s16x4*)&act[wv][sl][80 + g * 4] = z;
        }

        // ================= layer 2: 96 -> 72 (pad 80) =================
        f32x4 D2[5];
#pragma unroll
        for (int nt = 0; nt < 5; ++nt) {
            const float bb = b2L[nt * 16 + sl];
            D2[nt] = (f32x4){bb, bb, bb, bb};
        }
#pragma unroll
        for (int ks = 0; ks < 3; ++ks)
#pragma unroll
            for (int nt = 0; nt < 5; ++nt) {
                const s16x8 B = *(const s16x8*)&w2L[(nt * 3 + ks) * 512 + lane * 8];
                D2[nt] = __builtin_amdgcn_mfma_f32_16x16x32_bf16(A2[ks].v, B, D2[nt], 0, 0, 0);
            }
#pragma unroll
        for (int nt = 0; nt < 5; ++nt)
#pragma unroll
            for (int r = 0; r < 4; ++r)
                act[wv][g * 4 + r][nt * 16 + sl] = f2bf(fmaxf(D2[nt][r], 0.f));

        // layer-3 A-frags: h2 feats 0..95 (72..95 structurally zero)
        Frag A3[3];
#pragma unroll
        for (int ks = 0; ks < 3; ++ks)
            A3[ks].v = *(const s16x8*)&act[wv][sl][ks * 32 + g * 8];

        // ================= layer 3: 72 (pad 96) -> 64 =================
        f32x4 D3[4];
#pragma unroll
        for (int nt = 0; nt < 4; ++nt) {
            const float bb = b3L[nt * 16 + sl];
            D3[nt] = (f32x4){bb, bb, bb, bb};
        }
#pragma unroll
        for (int ks = 0; ks < 3; ++ks)
#pragma unroll
            for (int nt = 0; nt < 4; ++nt) {
                const s16x8 B = *(const s16x8*)&w3L[(nt * 3 + ks) * 512 + lane * 8];
                D3[nt] = __builtin_amdgcn_mfma_f32_16x16x32_bf16(A3[ks].v, B, D3[nt], 0, 0, 0);
            }

        // ===== epilogue: row norm; accumulate s/uu across passes =====
        float ffr[4];
#pragma unroll
        for (int r = 0; r < 4; ++r) {
            float a = 0.f;
#pragma unroll
            for (int nt = 0; nt < 4; ++nt)
                a = fmaf(D3[nt][r], D3[nt][r], a);
            ffr[r] = a;
        }
#pragma unroll
        for (int r = 0; r < 4; ++r) {
            ffr[r] += __shfl_xor(ffr[r], 1, 64);
            ffr[r] += __shfl_xor(ffr[r], 2, 64);
            ffr[r] += __shfl_xor(ffr[r], 4, 64);
            ffr[r] += __shfl_xor(ffr[r], 8, 64);
        }
        float inv[4];
#pragma unroll
        for (int r = 0; r < 4; ++r) {
            inv[r] = 1.f / fmaxf(sqrtf(ffr[r]), EPSF);
            uu_part = fmaf(ffr[r] * inv[r], inv[r], uu_part);  // dup x16 over sl
        }
#pragma unroll
        for (int nt = 0; nt < 4; ++nt)
#pragma unroll
            for (int r = 0; r < 4; ++r)
                s_part[nt] = fmaf(D3[nt][r], inv[r], s_part[nt]);
    }

    // cross-g reduction (once, after all passes) — identical to R7
#pragma unroll
    for (int nt = 0; nt < 4; ++nt) {
        s_part[nt] += __shfl_xor(s_part[nt], 16, 64);
        s_part[nt] += __shfl_xor(s_part[nt], 32, 64);
    }
    uu_part += __shfl_xor(uu_part, 16, 64);
    uu_part += __shfl_xor(uu_part, 32, 64);

    if (g == 0) {
#pragma unroll
        for (int nt = 0; nt < 4; ++nt) sred[wv][nt * 16 + sl] = s_part[nt];
    }
    if (lane == 0) uured[wv] = uu_part * 0.0625f;
    __syncthreads();

    if (tid < 64) {
        const float t = sred[0][tid] + sred[1][tid] + sred[2][tid] + sred[3][tid];
        atomicAdd(&acc[tid], t);
    }
    if (tid == 0)
        atomicAdd(&acc[64], uured[0] + uured[1] + uured[2] + uured[3]);
}

__global__ void finalize_k(const float* __restrict__ acc, float* __restrict__ out)
{
    float s = acc[threadIdx.x];
    float d = s * s;
#pragma unroll
    for (int off = 32; off > 0; off >>= 1)
        d += __shfl_xor(d, off, 64);
    if (threadIdx.x == 0)
        out[0] = 0.5f * (d - acc[64]) / (float)NROWS;
}

extern "C" void kernel_launch(void* const* d_in, const int* in_sizes, int n_in,
                              void* d_out, int out_size, void* d_ws, size_t ws_size,
                              hipStream_t stream)
{
    const float* x  = (const float*)d_in[0];
    const float* W1 = (const float*)d_in[1];
    const float* b1 = (const float*)d_in[2];
    const float* W2 = (const float*)d_in[3];
    const float* b2 = (const float*)d_in[4];
    const float* W3 = (const float*)d_in[5];
    const float* b3 = (const float*)d_in[6];

    char* ws = (char*)d_ws;
    float*          acc = (float*)ws;                      // 1 KB
    unsigned short* w1f = (unsigned short*)(ws + 1024);    // 24576 B
    unsigned short* w2f = (unsigned short*)(ws + 25600);   // 15360 B
    unsigned short* w3f = (unsigned short*)(ws + 40960);   // 12288 B
    float*          b1p = (float*)(ws + 53248);            // 384 B
    float*          b2p = (float*)(ws + 53632);            // 320 B
    float*          b3p = (float*)(ws + 53952);            // 256 B

    hipMemsetAsync(acc, 0, 1024, stream);
    repack<<<52, 64, 0, stream>>>(W1, b1, W2, b2, W3, b3, w1f, w2f, w3f, b1p, b2p, b3p);
    // 512 blocks x 4 waves x 8 passes x 16 rows = 262144 rows
    mlp_main<<<NROWS / (4 * PASSES * 16), 256, 0, stream>>>(
        x, (const f32x4*)(ws + 1024), acc);
    finalize_k<<<1, 64, 0, stream>>>(acc, (float*)d_out);
}